// Round 6
// baseline (891.067 us; speedup 1.0000x reference)
//
#include <hip/hip_runtime.h>

// GeneralizedInteractionNet on MI355X (gfx950). R6: 4 waves/SIMD overcommit.
//
// Per layer:  M[n,D,d] = W[n,D,d]*h[n,d]
//   GEMM1: C[b,i,D] = sum_d Bi[b,i,d] * M[n,D,d]
//   GEMM2: R[b,i,D] = sum_f AT[n,i,f] * B0T[b,D,f]^T
//   out[b,n,D] = sum_i C[b,i,D]*R[b,i,D]
// i padded 40->64 (2 row tiles of 32); f padded 40->48 (3 K-steps of 16).
// Padding garbage annihilated by exact zeros in AT (rows i>=40, cols f>=40).
//
// R5 post-mortem: MfmaUtil 45.8% == issued-MFMA-cycles/duration exactly
// (30.1 us pipe-time / 65.6 us). 2 waves/SIMD can't fill the other half
// (barrier vmcnt drains, LDS latency, combine chains). Row-packing to cut
// the 1.72x padding was evaluated: combine row-remap VALU ~= MFMA saved.
// R6: single-buffer LDS (14.3 KB -> 8 blocks/CU), nsplit 4 (10 n/block),
// launch_bounds(128,4) -> 4096 waves = 16/CU = 4 waves/SIMD, barriers
// decoupled across 8 independent blocks per CU.

typedef __bf16 bf16x8 __attribute__((ext_vector_type(8)));
typedef float  f32x16 __attribute__((ext_vector_type(16)));

constexpr int BATCH = 2048;
constexpr int FDIM  = 40;
constexpr int DDIM  = 64;
constexpr int LAY   = 3;
constexpr int IPAD  = 64;   // i padded: 2 row-tiles of 32
constexpr int FPAD  = 48;   // f padded: 3 K-steps of 16
constexpr int NSPL  = 4;    // n-loop split across 4 blocks
constexpr int NPB   = FDIM / NSPL;                // 10 n per block
constexpr int MB_BYTES  = DDIM * DDIM * 2;        // 8192
constexpr int AT_BYTES  = IPAD * FPAD * 2;        // 6144
constexpr int BUF_BYTES = MB_BYTES + AT_BYTES;    // 14336 (single buffer)

__device__ __forceinline__ unsigned short f2bf(float f) {
  union { float f; unsigned u; } v; v.f = f;
  unsigned r = v.u + 0x7fff + ((v.u >> 16) & 1);   // round-to-nearest-even
  return (unsigned short)(r >> 16);
}

// async 16B global->LDS; LDS dest = wave-uniform base + lane*16
__device__ __forceinline__ void async16(const void* g, void* l) {
  __builtin_amdgcn_global_load_lds(
      (const __attribute__((address_space(1))) unsigned int*)g,
      (__attribute__((address_space(3))) unsigned int*)l, 16, 0, 0);
}

// Prep, 4 segments:
//  M[l,n,D,d]  = W*h (bf16, natural layout)
//  AT[l,n,i64,f48] = alpha[l,f,i,n], zero-padded (i>=40 or f>=40 -> 0)
//  B0b[b,f,d]  = bf16(inputs)          (Bi operand for layer 0)
//  B0T[b,d,f48]= bf16(inputs[b,f,d]), f>=40 -> 0   (GEMM2 B operand)
__global__ void prep_k(const float* __restrict__ W, const float* __restrict__ h,
                       const float* __restrict__ alpha, const float* __restrict__ inputs,
                       unsigned short* __restrict__ M, unsigned short* __restrict__ AT,
                       unsigned short* __restrict__ B0b, unsigned short* __restrict__ B0T) {
  int i = blockIdx.x * blockDim.x + threadIdx.x;
  const int nM  = LAY * FDIM * DDIM * DDIM;   // 491520
  const int nAT = LAY * FDIM * IPAD * FPAD;   // 368640
  const int nB  = BATCH * FDIM * DDIM;        // 5242880
  const int nT  = BATCH * DDIM * FPAD;        // 6291456
  if (i < nM) {
    int d  = i & 63;
    int ln = i >> 12;
    M[i] = f2bf(W[i] * h[ln * DDIM + d]);
    return;
  }
  i -= nM;
  if (i < nAT) {
    int f  = i % FPAD;
    int ii = (i / FPAD) % IPAD;
    int n  = (i / (FPAD * IPAD)) % FDIM;
    int l  = i / (FPAD * IPAD * FDIM);
    float v = 0.f;
    if (f < FDIM && ii < FDIM)
      v = alpha[(((size_t)l * FDIM + f) * FDIM + ii) * FDIM + n];
    AT[i] = f2bf(v);
    return;
  }
  i -= nAT;
  if (i < nB) { B0b[i] = f2bf(inputs[i]); return; }
  i -= nB;
  if (i >= nT) return;
  int b   = i / (DDIM * FPAD);
  int rem = i - b * (DDIM * FPAD);
  int d   = rem / FPAD;
  int f   = rem - d * FPAD;
  B0T[i] = (f < FDIM) ? f2bf(inputs[((size_t)b * FDIM + f) * DDIM + d]) : (unsigned short)0;
}

// mfma_f32_32x32x16_bf16 conventions:
//   A[m=lane&31][k=8*(lane>>5)+j]  B[k=8*(lane>>5)+j][col=lane&31]
//   C/D: col=lane&31, row=(reg&3)+8*(reg>>2)+4*(lane>>5)   [HW-verified]
template <bool FINAL>
__global__ __launch_bounds__(128, 4) void layer_k(
    const unsigned short* __restrict__ Bi,   // bf16 [B][40][64] (prev layer / B0b)
    const unsigned short* __restrict__ B0T,  // bf16 [B][64][48]
    const unsigned short* __restrict__ Mt,   // [40][64][64] bf16
    const unsigned short* __restrict__ ATt,  // [40][64][48] bf16 zero-padded
    void* __restrict__ outp)                 // bf16 intermediate or f32 final
{
  __shared__ __align__(16) unsigned short smem[BUF_BYTES / 2];

  const int tid  = threadIdx.x;
  const int lane = tid & 63;
  const int w    = tid >> 6;                  // wave in block (0,1)
  const int c    = lane & 31;
  const int h    = lane >> 5;
  const int bg   = blockIdx.x >> 2;           // b-group: 4 consecutive b
  const int nBase = (blockIdx.x & 3) * NPB;   // this block's n range
  const int bb   = bg * 4 + w * 2;            // wave's first batch element

  // Stage M[n] (chunk-XOR-swizzled) + AT[n] into the single LDS buffer.
  auto stage = [&](int n) {
    const unsigned short* Mn = Mt  + n * (DDIM * DDIM);
    const unsigned short* An = ATt + n * (IPAD * FPAD);
    char* base = (char*)smem;
#pragma unroll
    for (int r = 0; r < 4; ++r) {             // 8KB of M
      int p  = r * 128 + tid;
      int D  = p >> 3, pc = p & 7;
      int cd = pc ^ (D & 7);
      async16(Mn + D * DDIM + cd * 8, base + r * 2048 + w * 1024);
    }
#pragma unroll
    for (int r = 0; r < 3; ++r)               // 6KB of AT
      async16(An + r * 1024 + tid * 8, base + MB_BYTES + r * 2048 + w * 1024);
  };

  // ---- wave-constant register fragments ----
  // aBi[b2][it][ks]: GEMM1 A (rows i, k=d); rows>=40 clamped (killed by R=0 rows).
  bf16x8 aBi[2][2][4];
#pragma unroll
  for (int b2 = 0; b2 < 2; ++b2)
#pragma unroll
    for (int it = 0; it < 2; ++it) {
      int row = it * 32 + c; if (row > FDIM - 1) row = FDIM - 1;
#pragma unroll
      for (int ks = 0; ks < 4; ++ks)
        aBi[b2][it][ks] = *reinterpret_cast<const bf16x8*>(
            Bi + ((size_t)(bb + b2) * FDIM + row) * DDIM + ks * 16 + h * 8);
    }

  // bT[b2][dt][ks]: GEMM2 B = B0T[b][D][f], contiguous 16B per lane.
  bf16x8 bT[2][2][3];
#pragma unroll
  for (int b2 = 0; b2 < 2; ++b2)
#pragma unroll
    for (int dt = 0; dt < 2; ++dt)
#pragma unroll
      for (int ks = 0; ks < 3; ++ks)
        bT[b2][dt][ks] = *reinterpret_cast<const bf16x8*>(
            B0T + ((size_t)(bb + b2) * DDIM + dt * 32 + c) * FPAD + ks * 16 + h * 8);

  for (int ln = 0; ln < NPB; ++ln) {
    const int n = nBase + ln;
    stage(n);
    __syncthreads();                          // staging drained (vmcnt0 at barrier)

    const char* bufp = (const char*)smem;

    // mb[dt][ks]: GEMM1 B from swizzled M: row D, phys chunk = cd ^ (D&7)
    bf16x8 mb[2][4];
#pragma unroll
    for (int dt = 0; dt < 2; ++dt)
#pragma unroll
      for (int ks = 0; ks < 4; ++ks) {
        int pc = (ks * 2 + h) ^ (c & 7);
        mb[dt][ks] = *reinterpret_cast<const bf16x8*>(
            bufp + (dt * 32 + c) * 128 + pc * 16);
      }

    float pout[2][2] = {{0.f, 0.f}, {0.f, 0.f}};   // [b2][dt]

#pragma unroll
    for (int it = 0; it < 2; ++it) {
      bf16x8 at[3];
#pragma unroll
      for (int ks = 0; ks < 3; ++ks)
        at[ks] = *reinterpret_cast<const bf16x8*>(
            bufp + MB_BYTES + ((it * 32 + c) * FPAD + ks * 16 + h * 8) * 2);

#pragma unroll
      for (int dt = 0; dt < 2; ++dt) {
        // Two independent (b2) chains interleaved -> MFMA pipe stays fed.
        f32x16 aC0 = {0,0,0,0,0,0,0,0,0,0,0,0,0,0,0,0};
        f32x16 aC1 = {0,0,0,0,0,0,0,0,0,0,0,0,0,0,0,0};
        f32x16 aR0 = {0,0,0,0,0,0,0,0,0,0,0,0,0,0,0,0};
        f32x16 aR1 = {0,0,0,0,0,0,0,0,0,0,0,0,0,0,0,0};
#pragma unroll
        for (int ks = 0; ks < 4; ++ks) {
          aC0 = __builtin_amdgcn_mfma_f32_32x32x16_bf16(aBi[0][it][ks], mb[dt][ks], aC0, 0, 0, 0);
          aC1 = __builtin_amdgcn_mfma_f32_32x32x16_bf16(aBi[1][it][ks], mb[dt][ks], aC1, 0, 0, 0);
        }
#pragma unroll
        for (int ks = 0; ks < 3; ++ks) {
          aR0 = __builtin_amdgcn_mfma_f32_32x32x16_bf16(at[ks], bT[0][dt][ks], aR0, 0, 0, 0);
          aR1 = __builtin_amdgcn_mfma_f32_32x32x16_bf16(at[ks], bT[1][dt][ks], aR1, 0, 0, 0);
        }
        // Combine: 4 independent partial chains per b2 (depth 4, not 16).
        {
          float t0 = 0.f, t1 = 0.f, t2 = 0.f, t3 = 0.f;
#pragma unroll
          for (int r = 0; r < 4; ++r) {
            t0 += aC0[r] * aR0[r];         t1 += aC0[r + 4] * aR0[r + 4];
            t2 += aC0[r + 8] * aR0[r + 8]; t3 += aC0[r + 12] * aR0[r + 12];
          }
          pout[0][dt] += (t0 + t1) + (t2 + t3);
        }
        {
          float t0 = 0.f, t1 = 0.f, t2 = 0.f, t3 = 0.f;
#pragma unroll
          for (int r = 0; r < 4; ++r) {
            t0 += aC1[r] * aR1[r];         t1 += aC1[r + 4] * aR1[r + 4];
            t2 += aC1[r + 8] * aR1[r + 8]; t3 += aC1[r + 12] * aR1[r + 12];
          }
          pout[1][dt] += (t0 + t1) + (t2 + t3);
        }
      }
    }

    // finish i-sum across lane halves; lane stores D=lane (coalesced)
#pragma unroll
    for (int b2 = 0; b2 < 2; ++b2) {
      float v0 = pout[b2][0] + __shfl_xor(pout[b2][0], 32, 64);
      float v1 = pout[b2][1] + __shfl_xor(pout[b2][1], 32, 64);
      float val = h ? v1 : v0;
      size_t off = ((size_t)(bb + b2) * FDIM + n) * DDIM + lane;
      if (FINAL) ((float*)outp)[off] = val;
      else       ((unsigned short*)outp)[off] = f2bf(val);
    }

    __syncthreads();                          // all reads of buf done before next stage
  }
}

extern "C" void kernel_launch(void* const* d_in, const int* in_sizes, int n_in,
                              void* d_out, int out_size, void* d_ws, size_t ws_size,
                              hipStream_t stream) {
  const float* inputs = (const float*)d_in[0];  // [2048,40,64]
  const float* W      = (const float*)d_in[1];  // [3,40,64,64]
  const float* alpha  = (const float*)d_in[2];  // [3,40,40,40]
  const float* h      = (const float*)d_in[3];  // [3,40,64,1]

  char* ws = (char*)d_ws;
  const size_t S   = (size_t)BATCH * FDIM * DDIM * 2;   // 10.49 MB bf16 buffer
  const size_t ST  = (size_t)BATCH * DDIM * FPAD * 2;   // 12.58 MB B0T
  unsigned short* Bi1 = (unsigned short*)(ws);
  unsigned short* Bi2 = (unsigned short*)(ws + S);
  unsigned short* B0b = (unsigned short*)(ws + 2 * S);
  unsigned short* B0T = (unsigned short*)(ws + 3 * S);
  unsigned short* Mb  = (unsigned short*)(ws + 3 * S + ST);
  unsigned short* ATb = (unsigned short*)(ws + 3 * S + ST + (size_t)LAY * FDIM * DDIM * DDIM * 2);

  const int nPrep = LAY * FDIM * DDIM * DDIM + LAY * FDIM * IPAD * FPAD
                  + BATCH * FDIM * DDIM + BATCH * DDIM * FPAD;
  prep_k<<<(nPrep + 255) / 256, 256, 0, stream>>>(W, h, alpha, inputs, Mb, ATb, B0b, B0T);

  dim3 grid(BATCH / 4 * NSPL), blk(128);   // 2048 blocks: nsplit 4
  const size_t mL = (size_t)FDIM * DDIM * DDIM;
  const size_t aL = (size_t)FDIM * IPAD * FPAD;
  layer_k<false><<<grid, blk, 0, stream>>>(B0b, B0T, Mb, ATb, Bi1);
  layer_k<false><<<grid, blk, 0, stream>>>(Bi1, B0T, Mb + mL, ATb + aL, Bi2);
  layer_k<true ><<<grid, blk, 0, stream>>>(Bi2, B0T, Mb + 2 * mL, ATb + 2 * aL, d_out);
}

// Round 7
// 292.691 us; speedup vs baseline: 3.0444x; 3.0444x over previous
//
#include <hip/hip_runtime.h>

// GeneralizedInteractionNet on MI355X (gfx950). R7: D-split waves for
// 4 waves/SIMD under the unified VGPR+AGPR cap.
//
// Per layer:  M[n,D,d] = W[n,D,d]*h[n,d]
//   GEMM1: C[b,i,D] = sum_d Bi[b,i,d] * M[n,D,d]
//   GEMM2: R[b,i,D] = sum_f AT[n,i,f] * B0T[b,D,f]^T
//   out[b,n,D] = sum_i C[b,i,D]*R[b,i,D]
// i padded 40->64 (2 row tiles of 32); f padded 40->48 (3 K-steps of 16).
// Padding garbage annihilated by exact zeros in AT (rows i>=40, cols f>=40).
//
// R6 post-mortem: launch_bounds caps the UNIFIED VGPR+AGPR file. (128,4)
// = 128 total; acc=64 AGPR left 64 VGPR for a 112-VGPR live set -> spill
// (864 MB FETCH). R5's wave (2 b, both dt) needs ~176 total = 2 waves/SIMD
// max. R7: wave = (b, D-half): aBi 32 + bT 12 + mb 16 + at 12 + acc 32
// + misc ~= 118 <= 128 -> 4 waves/SIMD legit. Block = 4 waves = 2b x 2dt
// sharing staged M[n]/AT[n] (double-buffered, as R5). Grid 1024, full
// n-loop -> 4096 waves = 16/CU, 4 blocks/CU (LDS 115 KB).

typedef __bf16 bf16x8 __attribute__((ext_vector_type(8)));
typedef float  f32x16 __attribute__((ext_vector_type(16)));

constexpr int BATCH = 2048;
constexpr int FDIM  = 40;
constexpr int DDIM  = 64;
constexpr int LAY   = 3;
constexpr int IPAD  = 64;   // i padded: 2 row-tiles of 32
constexpr int FPAD  = 48;   // f padded: 3 K-steps of 16
constexpr int MB_BYTES  = DDIM * DDIM * 2;        // 8192
constexpr int AT_BYTES  = IPAD * FPAD * 2;        // 6144
constexpr int BUF_BYTES = MB_BYTES + AT_BYTES;    // 14336

__device__ __forceinline__ unsigned short f2bf(float f) {
  union { float f; unsigned u; } v; v.f = f;
  unsigned r = v.u + 0x7fff + ((v.u >> 16) & 1);   // round-to-nearest-even
  return (unsigned short)(r >> 16);
}

// async 16B global->LDS; LDS dest = wave-uniform base + lane*16
__device__ __forceinline__ void async16(const void* g, void* l) {
  __builtin_amdgcn_global_load_lds(
      (const __attribute__((address_space(1))) unsigned int*)g,
      (__attribute__((address_space(3))) unsigned int*)l, 16, 0, 0);
}

// Prep, 4 segments:
//  M[l,n,D,d]  = W*h (bf16, natural layout)
//  AT[l,n,i64,f48] = alpha[l,f,i,n], zero-padded (i>=40 or f>=40 -> 0)
//  B0b[b,f,d]  = bf16(inputs)          (Bi operand for layer 0)
//  B0T[b,d,f48]= bf16(inputs[b,f,d]), f>=40 -> 0   (GEMM2 B operand)
__global__ void prep_k(const float* __restrict__ W, const float* __restrict__ h,
                       const float* __restrict__ alpha, const float* __restrict__ inputs,
                       unsigned short* __restrict__ M, unsigned short* __restrict__ AT,
                       unsigned short* __restrict__ B0b, unsigned short* __restrict__ B0T) {
  int i = blockIdx.x * blockDim.x + threadIdx.x;
  const int nM  = LAY * FDIM * DDIM * DDIM;   // 491520
  const int nAT = LAY * FDIM * IPAD * FPAD;   // 368640
  const int nB  = BATCH * FDIM * DDIM;        // 5242880
  const int nT  = BATCH * DDIM * FPAD;        // 6291456
  if (i < nM) {
    int d  = i & 63;
    int ln = i >> 12;
    M[i] = f2bf(W[i] * h[ln * DDIM + d]);
    return;
  }
  i -= nM;
  if (i < nAT) {
    int f  = i % FPAD;
    int ii = (i / FPAD) % IPAD;
    int n  = (i / (FPAD * IPAD)) % FDIM;
    int l  = i / (FPAD * IPAD * FDIM);
    float v = 0.f;
    if (f < FDIM && ii < FDIM)
      v = alpha[(((size_t)l * FDIM + f) * FDIM + ii) * FDIM + n];
    AT[i] = f2bf(v);
    return;
  }
  i -= nAT;
  if (i < nB) { B0b[i] = f2bf(inputs[i]); return; }
  i -= nB;
  if (i >= nT) return;
  int b   = i / (DDIM * FPAD);
  int rem = i - b * (DDIM * FPAD);
  int d   = rem / FPAD;
  int f   = rem - d * FPAD;
  B0T[i] = (f < FDIM) ? f2bf(inputs[((size_t)b * FDIM + f) * DDIM + d]) : (unsigned short)0;
}

// mfma_f32_32x32x16_bf16 conventions:
//   A[m=lane&31][k=8*(lane>>5)+j]  B[k=8*(lane>>5)+j][col=lane&31]
//   C/D: col=lane&31, row=(reg&3)+8*(reg>>2)+4*(lane>>5)   [HW-verified]
template <bool FINAL>
__global__ __launch_bounds__(256, 4) void layer_k(
    const unsigned short* __restrict__ Bi,   // bf16 [B][40][64] (prev layer / B0b)
    const unsigned short* __restrict__ B0T,  // bf16 [B][64][48]
    const unsigned short* __restrict__ Mt,   // [40][64][64] bf16
    const unsigned short* __restrict__ ATt,  // [40][64][48] bf16 zero-padded
    void* __restrict__ outp)                 // bf16 intermediate or f32 final
{
  __shared__ __align__(16) unsigned short smem[2 * BUF_BYTES / 2];

  const int tid  = threadIdx.x;
  const int lane = tid & 63;
  const int w    = tid >> 6;                  // wave (0..3)
  const int b2   = w >> 1;                    // wave's batch element (0,1)
  const int dt   = w & 1;                     // wave's D-half (0,1)
  const int c    = lane & 31;
  const int h    = lane >> 5;
  const int b    = blockIdx.x * 2 + b2;

  // Stage M[n] (chunk-XOR-swizzled) + AT[n] into LDS buffer `buf`.
  // 4 waves cooperate: M = 2 rounds x 4 KB, AT = 1 round + half round.
  auto stage = [&](int n, int buf) {
    const unsigned short* Mn = Mt  + n * (DDIM * DDIM);
    const unsigned short* An = ATt + n * (IPAD * FPAD);
    char* base = (char*)smem + buf * BUF_BYTES;
#pragma unroll
    for (int r = 0; r < 2; ++r) {             // 8KB of M
      int p  = r * 256 + tid;                 // 16B-chunk index
      int D  = p >> 3, pc = p & 7;
      int cd = pc ^ (D & 7);
      async16(Mn + D * DDIM + cd * 8, base + r * 4096 + w * 1024);
    }
    // AT: 6 KB = 384 chunks; round 0 all waves, round 1 waves 0,1 only.
    async16(An + tid * 8, base + MB_BYTES + w * 1024);
    if (w < 2)
      async16(An + (256 + tid) * 8, base + MB_BYTES + 4096 + w * 1024);
  };

  // ---- wave-constant register fragments ----
  // aBi[it][ks]: GEMM1 A (rows i, k=d); rows>=40 clamped (killed by R=0 rows).
  bf16x8 aBi[2][4];
#pragma unroll
  for (int it = 0; it < 2; ++it) {
    int row = it * 32 + c; if (row > FDIM - 1) row = FDIM - 1;
#pragma unroll
    for (int ks = 0; ks < 4; ++ks)
      aBi[it][ks] = *reinterpret_cast<const bf16x8*>(
          Bi + ((size_t)b * FDIM + row) * DDIM + ks * 16 + h * 8);
  }

  // bT[ks]: GEMM2 B = B0T[b][D=dt*32+c][f], contiguous 16B per lane.
  bf16x8 bT[3];
#pragma unroll
  for (int ks = 0; ks < 3; ++ks)
    bT[ks] = *reinterpret_cast<const bf16x8*>(
        B0T + ((size_t)b * DDIM + dt * 32 + c) * FPAD + ks * 16 + h * 8);

  stage(0, 0);

  for (int n = 0; n < FDIM; ++n) {
    __syncthreads();                          // drains staging of buf[n&1]
    const int buf = n & 1;
    if (n + 1 < FDIM) stage(n + 1, buf ^ 1);  // prefetch overlaps compute

    const char* bufp = (const char*)smem + buf * BUF_BYTES;

    // mb[ks]: GEMM1 B from swizzled M, rows D = dt*32+c only.
    bf16x8 mb[4];
#pragma unroll
    for (int ks = 0; ks < 4; ++ks) {
      int D  = dt * 32 + c;
      int pc = (ks * 2 + h) ^ (D & 7);
      mb[ks] = *reinterpret_cast<const bf16x8*>(bufp + D * 128 + pc * 16);
    }

    float pout = 0.f;
#pragma unroll
    for (int it = 0; it < 2; ++it) {
      bf16x8 at[3];
#pragma unroll
      for (int ks = 0; ks < 3; ++ks)
        at[ks] = *reinterpret_cast<const bf16x8*>(
            bufp + MB_BYTES + ((it * 32 + c) * FPAD + ks * 16 + h * 8) * 2);

      f32x16 aC = {0,0,0,0,0,0,0,0,0,0,0,0,0,0,0,0};
      f32x16 aR = {0,0,0,0,0,0,0,0,0,0,0,0,0,0,0,0};
#pragma unroll
      for (int ks = 0; ks < 4; ++ks)
        aC = __builtin_amdgcn_mfma_f32_32x32x16_bf16(aBi[it][ks], mb[ks], aC, 0, 0, 0);
#pragma unroll
      for (int ks = 0; ks < 3; ++ks)
        aR = __builtin_amdgcn_mfma_f32_32x32x16_bf16(at[ks], bT[ks], aR, 0, 0, 0);

      // Combine: 4 independent partial chains (depth 4).
      float t0 = 0.f, t1 = 0.f, t2 = 0.f, t3 = 0.f;
#pragma unroll
      for (int r = 0; r < 4; ++r) {
        t0 += aC[r] * aR[r];         t1 += aC[r + 4] * aR[r + 4];
        t2 += aC[r + 8] * aR[r + 8]; t3 += aC[r + 12] * aR[r + 12];
      }
      pout += (t0 + t1) + (t2 + t3);
    }

    // finish i-sum across lane halves; lanes 0..31 store D = dt*32 + lane.
    float v = pout + __shfl_xor(pout, 32, 64);
    if (lane < 32) {
      size_t off = ((size_t)b * FDIM + n) * DDIM + dt * 32 + lane;
      if (FINAL) ((float*)outp)[off] = v;
      else       ((unsigned short*)outp)[off] = f2bf(v);
    }
  }
}

extern "C" void kernel_launch(void* const* d_in, const int* in_sizes, int n_in,
                              void* d_out, int out_size, void* d_ws, size_t ws_size,
                              hipStream_t stream) {
  const float* inputs = (const float*)d_in[0];  // [2048,40,64]
  const float* W      = (const float*)d_in[1];  // [3,40,64,64]
  const float* alpha  = (const float*)d_in[2];  // [3,40,40,40]
  const float* h      = (const float*)d_in[3];  // [3,40,64,1]

  char* ws = (char*)d_ws;
  const size_t S   = (size_t)BATCH * FDIM * DDIM * 2;   // 10.49 MB bf16 buffer
  const size_t ST  = (size_t)BATCH * DDIM * FPAD * 2;   // 12.58 MB B0T
  unsigned short* Bi1 = (unsigned short*)(ws);
  unsigned short* Bi2 = (unsigned short*)(ws + S);
  unsigned short* B0b = (unsigned short*)(ws + 2 * S);
  unsigned short* B0T = (unsigned short*)(ws + 3 * S);
  unsigned short* Mb  = (unsigned short*)(ws + 3 * S + ST);
  unsigned short* ATb = (unsigned short*)(ws + 3 * S + ST + (size_t)LAY * FDIM * DDIM * DDIM * 2);

  const int nPrep = LAY * FDIM * DDIM * DDIM + LAY * FDIM * IPAD * FPAD
                  + BATCH * FDIM * DDIM + BATCH * DDIM * FPAD;
  prep_k<<<(nPrep + 255) / 256, 256, 0, stream>>>(W, h, alpha, inputs, Mb, ATb, B0b, B0T);

  dim3 grid(BATCH / 2), blk(256);   // 1024 blocks x 4 waves = 4 waves/SIMD
  const size_t mL = (size_t)FDIM * DDIM * DDIM;
  const size_t aL = (size_t)FDIM * IPAD * FPAD;
  layer_k<false><<<grid, blk, 0, stream>>>(B0b, B0T, Mb, ATb, Bi1);
  layer_k<false><<<grid, blk, 0, stream>>>(Bi1, B0T, Mb + mL, ATb + aL, Bi2);
  layer_k<true ><<<grid, blk, 0, stream>>>(Bi2, B0T, Mb + 2 * mL, ATb + 2 * aL, d_out);
}